// Round 1
// baseline (91.616 us; speedup 1.0000x reference)
//
#include <hip/hip_runtime.h>
#include <hip/hip_bf16.h>
#include <math.h>

#define T_TOK 8192
#define DDIM  4096
#define NEXP  64
#define TOPK  8

// GEMM config
#define MTILE    128
#define BK       64
#define NTHREADS 256
#define A_STRIDE 132   // 128 + 4 pad floats; row = 528B (16B aligned), 2-way write conflicts only
#define B_STRIDE 68    // 64 + 4 pad floats;  row = 272B (16B aligned)

// C tile 128 tokens x 64 experts; thread frag 4 tokens x 8 experts.
__global__ __launch_bounds__(NTHREADS) void gemm_logits(
    const float* __restrict__ x, const float* __restrict__ gw,
    float* __restrict__ part, int S, int kprime)
{
    __shared__ float A_lds[BK * A_STRIDE];
    __shared__ float B_lds[BK * B_STRIDE];

    const int nmt  = T_TOK / MTILE;          // 64 M-tiles
    const int bid  = blockIdx.x;
    const int mt   = bid % nmt;
    const int s    = bid / nmt;
    const int m0   = mt * MTILE;
    const int kbeg = s * kprime;
    const int kend = kbeg + kprime;

    const int t  = threadIdx.x;
    const int tn = t & 7;    // expert group (8 experts)
    const int tm = t >> 3;   // token group (4 tokens), 0..31

    float acc[4][8];
    #pragma unroll
    for (int i = 0; i < 4; i++)
        #pragma unroll
        for (int j = 0; j < 8; j++) acc[i][j] = 0.f;

    for (int k0 = kbeg; k0 < kend; k0 += BK) {
        // ---- stage A: 128 tokens x 64 k (transposed into [k][m]) ----
        #pragma unroll
        for (int r = 0; r < 8; r++) {
            int idx = t + NTHREADS * r;      // float4 index over tile
            int m   = idx >> 4;              // 16 float4 per row
            int kq  = idx & 15;
            float4 v = *reinterpret_cast<const float4*>(
                x + (size_t)(m0 + m) * DDIM + k0 + kq * 4);
            A_lds[(kq * 4 + 0) * A_STRIDE + m] = v.x;
            A_lds[(kq * 4 + 1) * A_STRIDE + m] = v.y;
            A_lds[(kq * 4 + 2) * A_STRIDE + m] = v.z;
            A_lds[(kq * 4 + 3) * A_STRIDE + m] = v.w;
        }
        // ---- stage B: 64 experts x 64 k (transposed into [k][e]) ----
        #pragma unroll
        for (int r = 0; r < 4; r++) {
            int idx = t + NTHREADS * r;
            int e   = idx >> 4;
            int kq  = idx & 15;
            float4 v = *reinterpret_cast<const float4*>(
                gw + (size_t)e * DDIM + k0 + kq * 4);
            B_lds[(kq * 4 + 0) * B_STRIDE + e] = v.x;
            B_lds[(kq * 4 + 1) * B_STRIDE + e] = v.y;
            B_lds[(kq * 4 + 2) * B_STRIDE + e] = v.z;
            B_lds[(kq * 4 + 3) * B_STRIDE + e] = v.w;
        }
        __syncthreads();

        #pragma unroll 8
        for (int k = 0; k < BK; k++) {
            float4 a  = *reinterpret_cast<const float4*>(&A_lds[k * A_STRIDE + tm * 4]);
            float4 b0 = *reinterpret_cast<const float4*>(&B_lds[k * B_STRIDE + tn * 8]);
            float4 b1 = *reinterpret_cast<const float4*>(&B_lds[k * B_STRIDE + tn * 8 + 4]);
            const float av[4] = {a.x, a.y, a.z, a.w};
            const float bv[8] = {b0.x, b0.y, b0.z, b0.w, b1.x, b1.y, b1.z, b1.w};
            #pragma unroll
            for (int i = 0; i < 4; i++)
                #pragma unroll
                for (int j = 0; j < 8; j++)
                    acc[i][j] = fmaf(av[i], bv[j], acc[i][j]);
        }
        __syncthreads();
    }

    // ---- write partials: part[s][token][expert] ----
    float* pout = part + (size_t)s * T_TOK * NEXP + (size_t)m0 * NEXP;
    #pragma unroll
    for (int i = 0; i < 4; i++) {
        int row = tm * 4 + i;
        float4 w0 = make_float4(acc[i][0], acc[i][1], acc[i][2], acc[i][3]);
        float4 w1 = make_float4(acc[i][4], acc[i][5], acc[i][6], acc[i][7]);
        *reinterpret_cast<float4*>(&pout[(size_t)row * NEXP + tn * 8])     = w0;
        *reinterpret_cast<float4*>(&pout[(size_t)row * NEXP + tn * 8 + 4]) = w1;
    }
}

// One wave per token: reduce K-split partials, sigmoid, +bias, top-8, normalize.
__global__ __launch_bounds__(256) void reduce_topk(
    const float* __restrict__ part, const float* __restrict__ bias,
    float* __restrict__ out, int S)
{
    const int wave  = threadIdx.x >> 6;
    const int lane  = threadIdx.x & 63;
    const int token = blockIdx.x * 4 + wave;
    if (token >= T_TOK) return;

    float logit = 0.f;
    for (int s = 0; s < S; s++)
        logit += part[(size_t)s * T_TOK * NEXP + (size_t)token * NEXP + lane];

    float score  = 1.f / (1.f + expf(-logit));
    float biased = score + bias[lane];

    float my_sc = 0.f;
    int   my_idx = 0;
    float ssum  = 0.f;

    #pragma unroll
    for (int j = 0; j < TOPK; j++) {
        float v = biased;
        int   i = lane;
        #pragma unroll
        for (int off = 32; off >= 1; off >>= 1) {
            float ov = __shfl_xor(v, off);
            int   oi = __shfl_xor(i, off);
            if (ov > v || (ov == v && oi < i)) { v = ov; i = oi; }
        }
        // all lanes now agree on (v, i)
        float s_sel = __shfl(score, i);
        ssum += s_sel;
        if (lane == j) { my_idx = i; my_sc = s_sel; }
        if (lane == i) biased = -INFINITY;
    }

    if (lane < TOPK) {
        out[(size_t)token * TOPK + lane] = (float)my_idx;                     // indices (as f32)
        out[(size_t)T_TOK * TOPK + (size_t)token * TOPK + lane]
            = my_sc / (ssum + 1e-20f);                                        // weights
    }
}

extern "C" void kernel_launch(void* const* d_in, const int* in_sizes, int n_in,
                              void* d_out, int out_size, void* d_ws, size_t ws_size,
                              hipStream_t stream) {
    (void)in_sizes; (void)n_in; (void)out_size;
    const float* x    = (const float*)d_in[0];
    const float* gw   = (const float*)d_in[1];
    const float* bias = (const float*)d_in[2];
    float* out  = (float*)d_out;
    float* part = (float*)d_ws;

    const size_t per = (size_t)T_TOK * NEXP * sizeof(float); // 2 MiB per K-split slice
    size_t cap = ws_size / per;
    int S = (cap >= 8) ? 8 : (cap >= 4) ? 4 : (cap >= 2) ? 2 : 1;
    int kprime = DDIM / S;

    dim3 g1((T_TOK / MTILE) * S), b1(NTHREADS);
    gemm_logits<<<g1, b1, 0, stream>>>(x, gw, part, S, kprime);

    dim3 g2((T_TOK + 3) / 4), b2(256);
    reduce_topk<<<g2, b2, 0, stream>>>(part, bias, out, S);
}